// Round 8
// baseline (636.851 us; speedup 1.0000x reference)
//
#include <hip/hip_runtime.h>

// ---------------------------------------------------------------------------
// GIN model. R8: graph-pooling fused into k_mlp epilogue (LDS partials reusing
// dead As buffer + fp32 global atomics into pg); slot-0 pool reads fp32 x
// directly; pg fp32 (precision up); lin1 mgemm stages fp32 A; w1/w2 prep in
// one dispatch. k_agg/k_scatter at structural floors (R4/R5 evidence).
// ---------------------------------------------------------------------------

typedef __bf16 bf16x8 __attribute__((ext_vector_type(8)));
typedef float f32x4 __attribute__((ext_vector_type(4)));

static inline int ceil_div(int a, int b) { return (a + b - 1) / b; }

__device__ inline ushort bf_rne(float v) {
  unsigned u = __float_as_uint(v);
  return (ushort)((u + 0x7fffu + ((u >> 16) & 1u)) >> 16);
}
__device__ inline float bf2f(ushort u) { return __uint_as_float((unsigned)u << 16); }
__device__ inline float bf2f_lo(unsigned g) { return __uint_as_float(g << 16); }
__device__ inline float bf2f_hi(unsigned g) { return __uint_as_float(g & 0xffff0000u); }

// ---- CSR build ------------------------------------------------------------
__global__ void k_hist(const int* __restrict__ src, int* __restrict__ deg, int E) {
  int i = blockIdx.x * blockDim.x + threadIdx.x;
  if (i < E) atomicAdd(&deg[src[i]], 1);
}

__global__ __launch_bounds__(256) void k_scan1(const int* __restrict__ deg,
                                               int* __restrict__ excl,
                                               int* __restrict__ bsum, int N) {
  __shared__ int tsum[256];
  int b = blockIdx.x, t = threadIdx.x;
  int base = b * 1024 + t * 4;
  int v0 = 0, v1 = 0, v2 = 0, v3 = 0;
  if (base + 3 < N) {
    int4 q = *(const int4*)&deg[base];
    v0 = q.x; v1 = q.y; v2 = q.z; v3 = q.w;
  } else {
    if (base + 0 < N) v0 = deg[base + 0];
    if (base + 1 < N) v1 = deg[base + 1];
    if (base + 2 < N) v2 = deg[base + 2];
    if (base + 3 < N) v3 = deg[base + 3];
  }
  tsum[t] = v0 + v1 + v2 + v3;
  __syncthreads();
  for (int off = 1; off < 256; off <<= 1) {
    int x = (t >= off) ? tsum[t - off] : 0;
    __syncthreads();
    tsum[t] += x;
    __syncthreads();
  }
  int pre = (t == 0) ? 0 : tsum[t - 1];
  if (base < N)     excl[base]     = pre;
  if (base + 1 < N) excl[base + 1] = pre + v0;
  if (base + 2 < N) excl[base + 2] = pre + v0 + v1;
  if (base + 3 < N) excl[base + 3] = pre + v0 + v1 + v2;
  if (t == 255) bsum[b] = tsum[255];
}

__global__ __launch_bounds__(256) void k_scan2(const int* __restrict__ bsum,
                                               int* __restrict__ boff, int nb,
                                               int* __restrict__ rowptr_last) {
  __shared__ int s[256];
  int t = threadIdx.x;
  s[t] = (t < nb) ? bsum[t] : 0;
  __syncthreads();
  for (int off = 1; off < 256; off <<= 1) {
    int x = (t >= off) ? s[t - off] : 0;
    __syncthreads();
    s[t] += x;
    __syncthreads();
  }
  if (t < nb) boff[t] = (t == 0) ? 0 : s[t - 1];
  if (t == 255) *rowptr_last = s[255];
}

__global__ __launch_bounds__(256) void k_scan3(const int* __restrict__ excl,
                                               const int* __restrict__ boff,
                                               int* __restrict__ rowptr,
                                               int* __restrict__ cursor, int N) {
  int i = blockIdx.x * 256 + threadIdx.x;
  if (i < N) {
    int v = excl[i] + boff[i >> 10];
    rowptr[i] = v;
    cursor[i] = v;
  }
}

__global__ void k_scatter(const int* __restrict__ src, const int* __restrict__ dst,
                          const float* __restrict__ mask, int* __restrict__ cursor,
                          int2* __restrict__ sedge, int E) {
  int i = blockIdx.x * blockDim.x + threadIdx.x;
  if (i < E) {
    int s = src[i];
    int p = atomicAdd(&cursor[s], 1);
    sedge[p] = make_int2(dst[i], __float_as_int(mask[i]));
  }
}

// ---- fp32 -> bf16 conversion ---------------------------------------------
__global__ __launch_bounds__(256) void k_tobf16(const float* __restrict__ in,
                                                ushort* __restrict__ out, int n) {
  int base = (blockIdx.x * 256 + threadIdx.x) * 4;
  if (base + 3 < n) {
    float4 v = *(const float4*)&in[base];
    ushort4 o;
    o.x = bf_rne(v.x); o.y = bf_rne(v.y); o.z = bf_rne(v.z); o.w = bf_rne(v.w);
    *(ushort4*)&out[base] = o;
  } else {
    for (int k = base; k < n; ++k) out[k] = bf_rne(in[k]);
  }
}

// ---- weight prep: both MLP weight sets in one dispatch --------------------
// z < L: w1 matrix z;  z >= L: w2 matrix z-L.  All are 128x128.
__global__ __launch_bounds__(256) void k_prepw12(const float* __restrict__ W1,
                                                 const float* __restrict__ W2,
                                                 ushort* __restrict__ hi1,
                                                 ushort* __restrict__ hi2, int L) {
  __shared__ float t[32][33];
  int z = blockIdx.z;
  const float* Wm = (z < L) ? (W1 + (size_t)z * 128 * 128)
                            : (W2 + (size_t)(z - L) * 128 * 128);
  ushort* him = (z < L) ? (hi1 + (size_t)z * 128 * 128)
                        : (hi2 + (size_t)(z - L) * 128 * 128);
  int k0 = blockIdx.x * 32, n0 = blockIdx.y * 32;
  int tx = threadIdx.x & 31, ty = threadIdx.x >> 5;
#pragma unroll
  for (int r = 0; r < 32; r += 8)
    t[ty + r][tx] = Wm[(size_t)(k0 + ty + r) * 128 + n0 + tx];
  __syncthreads();
#pragma unroll
  for (int r = 0; r < 32; r += 8) {
    float v = t[tx][ty + r];
    him[(size_t)(n0 + ty + r) * 128 + k0 + tx] = bf_rne(v);
  }
}

// ---- weight prep for lin1: split hi/lo, transposed ------------------------
__global__ __launch_bounds__(256) void k_prepw(const float* __restrict__ W,
                                               ushort* __restrict__ hi,
                                               ushort* __restrict__ lo,
                                               int K, int N) {
  __shared__ float t[32][33];
  const float* Wm = W;
  int k0 = blockIdx.x * 32, n0 = blockIdx.y * 32;
  int tx = threadIdx.x & 31, ty = threadIdx.x >> 5;
#pragma unroll
  for (int r = 0; r < 32; r += 8)
    t[ty + r][tx] = Wm[(size_t)(k0 + ty + r) * N + n0 + tx];
  __syncthreads();
#pragma unroll
  for (int r = 0; r < 32; r += 8) {
    float v = t[tx][ty + r];
    size_t o = (size_t)(n0 + ty + r) * K + k0 + tx;
    ushort h = bf_rne(v);
    hi[o] = h;
    lo[o] = bf_rne(v - bf2f(h));
  }
}

// ---- per-node aggregation: 1 wave per node, lane carries 2 features -------
__global__ __launch_bounds__(128) void k_agg(const ushort* __restrict__ h,
                                             const int* __restrict__ rowptr,
                                             const int2* __restrict__ sedge,
                                             const float* __restrict__ eps, int layer,
                                             ushort* __restrict__ pooled, int N) {
  int v = blockIdx.x * 2 + (threadIdx.x >> 6);
  int lane = threadIdx.x & 63;
  if (v >= N) return;
  int beg = rowptr[v], end = rowptr[v + 1];
  float ax[8] = {}, ay[8] = {};
  int j = beg;
  for (; j + 8 <= end; j += 8) {
    int2 e[8];
    unsigned g[8];
#pragma unroll
    for (int q = 0; q < 8; ++q) e[q] = sedge[j + q];
#pragma unroll
    for (int q = 0; q < 8; ++q)
      g[q] = *(const unsigned*)&h[(size_t)e[q].x * 128 + lane * 2];
#pragma unroll
    for (int q = 0; q < 8; ++q) {
      float m = __int_as_float(e[q].y);
      ax[q] = fmaf(m, bf2f_lo(g[q]), ax[q]);
      ay[q] = fmaf(m, bf2f_hi(g[q]), ay[q]);
    }
  }
  for (; j + 2 <= end; j += 2) {
    int2 e0 = sedge[j], e1 = sedge[j + 1];
    unsigned g0 = *(const unsigned*)&h[(size_t)e0.x * 128 + lane * 2];
    unsigned g1 = *(const unsigned*)&h[(size_t)e1.x * 128 + lane * 2];
    ax[0] = fmaf(__int_as_float(e0.y), bf2f_lo(g0), ax[0]);
    ay[0] = fmaf(__int_as_float(e0.y), bf2f_hi(g0), ay[0]);
    ax[1] = fmaf(__int_as_float(e1.y), bf2f_lo(g1), ax[1]);
    ay[1] = fmaf(__int_as_float(e1.y), bf2f_hi(g1), ay[1]);
  }
  if (j < end) {
    int2 e = sedge[j];
    unsigned g = *(const unsigned*)&h[(size_t)e.x * 128 + lane * 2];
    float m = __int_as_float(e.y);
    ax[0] = fmaf(m, bf2f_lo(g), ax[0]);
    ay[0] = fmaf(m, bf2f_hi(g), ay[0]);
  }
  float sx = ((ax[0] + ax[1]) + (ax[2] + ax[3])) + ((ax[4] + ax[5]) + (ax[6] + ax[7]));
  float sy = ((ay[0] + ay[1]) + (ay[2] + ay[3])) + ((ay[4] + ay[5]) + (ay[6] + ay[7]));
  float ep = 1.0f + eps[layer];
  unsigned gs = *(const unsigned*)&h[(size_t)v * 128 + lane * 2];
  sx = fmaf(ep, bf2f_lo(gs), sx);
  sy = fmaf(ep, bf2f_hi(gs), sy);
  unsigned outw = (unsigned)bf_rne(sx) | ((unsigned)bf_rne(sy) << 16);
  *(unsigned*)&pooled[(size_t)v * 128 + lane * 2] = outw;
}

// ---- fused 2-layer MLP + graph-pool epilogue ------------------------------
// h_out = relu(relu(pooled@W1+b1)@W2+b2); per-graph sums of h_out (fp32,
// pre-rounding) accumulated into pgf[g*F + slotoff + d].
// LDS: As 16K (reused as pool scratch after GEMM1) + Ws 32K + H1s 16K = 64K.
__global__ __launch_bounds__(256) void k_mlp(
    const ushort* __restrict__ pooled,
    const ushort* __restrict__ w1t, const float* __restrict__ b1,
    const ushort* __restrict__ w2t, const float* __restrict__ b2,
    ushort* __restrict__ hout, const int* __restrict__ batch,
    float* __restrict__ pgf, int slotoff, int F, int N) {
  __shared__ ushort As[64][128];
  __shared__ ushort Ws[128][128];
  __shared__ ushort H1s[64][128];
  float* pgpart = (float*)As;                    // 8*128 f32 = 4KB
  int* bts = (int*)((char*)As + 4096);           // 64 ints
  int tid = threadIdx.x;
  int w = tid >> 6, lane = tid & 63;
  int row0 = blockIdx.x * 64;
  int wr = w >> 1, wc = w & 1;

  // stage A (pooled tile) + W1
#pragma unroll
  for (int i = 0; i < 4; ++i) {
    int f = i * 256 + tid;
    int r = f >> 4, c8 = (f & 15) * 8;
    int ksw = c8 ^ ((r & 7) << 3);
    if (row0 + r < N) {
      *(bf16x8*)&As[r][ksw] = *(const bf16x8*)&pooled[(size_t)(row0 + r) * 128 + c8];
    } else {
      ushort4 z = {0, 0, 0, 0};
      *(ushort4*)&As[r][ksw] = z;
      *(ushort4*)&As[r][ksw + 4] = z;
    }
  }
#pragma unroll
  for (int i = 0; i < 8; ++i) {
    int f = i * 256 + tid;
    int r = f >> 4, c8 = (f & 15) * 8;
    *(bf16x8*)&Ws[r][c8 ^ ((r & 7) << 3)] = *(const bf16x8*)&w1t[(size_t)r * 128 + c8];
  }
  __syncthreads();

  // GEMM1: waves 2x2, each 32 rows x 64 cols
  f32x4 acc[2][4];
#pragma unroll
  for (int m = 0; m < 2; ++m)
#pragma unroll
    for (int n = 0; n < 4; ++n) acc[m][n] = (f32x4){0.f, 0.f, 0.f, 0.f};
#pragma unroll
  for (int ks = 0; ks < 4; ++ks) {
    int kk = ks * 32 + (lane >> 4) * 8;
    bf16x8 a[2], b[4];
#pragma unroll
    for (int m = 0; m < 2; ++m) {
      int r = wr * 32 + m * 16 + (lane & 15);
      a[m] = *(bf16x8*)&As[r][kk ^ ((r & 7) << 3)];
    }
#pragma unroll
    for (int n = 0; n < 4; ++n) {
      int r = wc * 64 + n * 16 + (lane & 15);
      b[n] = *(bf16x8*)&Ws[r][kk ^ ((r & 7) << 3)];
    }
#pragma unroll
    for (int m = 0; m < 2; ++m)
#pragma unroll
      for (int n = 0; n < 4; ++n)
        acc[m][n] = __builtin_amdgcn_mfma_f32_16x16x32_bf16(a[m], b[n], acc[m][n], 0, 0, 0);
  }
#pragma unroll
  for (int m = 0; m < 2; ++m) {
    int rbase = wr * 32 + m * 16 + (lane >> 4) * 4;
#pragma unroll
    for (int n = 0; n < 4; ++n) {
      int col = wc * 64 + n * 16 + (lane & 15);
      float bb = b1[col];
#pragma unroll
      for (int r = 0; r < 4; ++r) {
        int row = rbase + r;
        float v = fmaxf(acc[m][n][r] + bb, 0.f);
        H1s[row][col ^ ((row & 7) << 3)] = bf_rne(v);
      }
    }
  }
  __syncthreads();   // all As reads + H1s writes complete

  // restage W2; repurpose As: zero pool partials + stage batch tile
#pragma unroll
  for (int i = 0; i < 8; ++i) {
    int f = i * 256 + tid;
    int r = f >> 4, c8 = (f & 15) * 8;
    *(bf16x8*)&Ws[r][c8 ^ ((r & 7) << 3)] = *(const bf16x8*)&w2t[(size_t)r * 128 + c8];
  }
  for (int idx = tid; idx < 1024; idx += 256) pgpart[idx] = 0.f;
  if (tid < 64) {
    int row = row0 + tid;
    bts[tid] = batch[(row < N) ? row : (N - 1)];
  }
  __syncthreads();

  int gmin = bts[0];
  int span = bts[63] - gmin + 1;
  bool fast = (span <= 8);

  // GEMM2
#pragma unroll
  for (int m = 0; m < 2; ++m)
#pragma unroll
    for (int n = 0; n < 4; ++n) acc[m][n] = (f32x4){0.f, 0.f, 0.f, 0.f};
#pragma unroll
  for (int ks = 0; ks < 4; ++ks) {
    int kk = ks * 32 + (lane >> 4) * 8;
    bf16x8 a[2], b[4];
#pragma unroll
    for (int m = 0; m < 2; ++m) {
      int r = wr * 32 + m * 16 + (lane & 15);
      a[m] = *(bf16x8*)&H1s[r][kk ^ ((r & 7) << 3)];
    }
#pragma unroll
    for (int n = 0; n < 4; ++n) {
      int r = wc * 64 + n * 16 + (lane & 15);
      b[n] = *(bf16x8*)&Ws[r][kk ^ ((r & 7) << 3)];
    }
#pragma unroll
    for (int m = 0; m < 2; ++m)
#pragma unroll
      for (int n = 0; n < 4; ++n)
        acc[m][n] = __builtin_amdgcn_mfma_f32_16x16x32_bf16(a[m], b[n], acc[m][n], 0, 0, 0);
  }
  // epilogue2: store bf16 h + accumulate graph-pool partials (fp32)
#pragma unroll
  for (int m = 0; m < 2; ++m) {
    int rlbase = wr * 32 + m * 16 + (lane >> 4) * 4;
#pragma unroll
    for (int n = 0; n < 4; ++n) {
      int col = wc * 64 + n * 16 + (lane & 15);
      float bb = b2[col];
#pragma unroll
      for (int r = 0; r < 4; ++r) {
        int rl = rlbase + r;
        int row = row0 + rl;
        if (row < N) {
          float v = fmaxf(acc[m][n][r] + bb, 0.f);
          hout[(size_t)row * 128 + col] = bf_rne(v);
          int g = bts[rl];
          if (fast)
            atomicAdd(&pgpart[(g - gmin) * 128 + col], v);
          else
            atomicAdd(&pgf[(size_t)g * F + slotoff + col], v);
        }
      }
    }
  }
  __syncthreads();
  if (fast) {
    int tot = span * 128;
    for (int idx = tid; idx < tot; idx += 256) {
      float v = pgpart[idx];
      if (v != 0.f)
        atomicAdd(&pgf[(size_t)(gmin + (idx >> 7)) * F + slotoff + (idx & 127)], v);
    }
  }
}

// ---- bf16-A / fp32-A MFMA GEMM (classifier lin1): split W -----------------
template <int RELU, int OUT_BF16, int SPLITW, int A_FP32>
__global__ __launch_bounds__(256) void k_mgemm(const void* __restrict__ A,
                                               const ushort* __restrict__ Wt_hi,
                                               const ushort* __restrict__ Wt_lo,
                                               const float* __restrict__ bias,
                                               void* __restrict__ Cout,
                                               int M, int N, int K) {
  __shared__ ushort As[64][128];
  __shared__ ushort Ws_hi[64][128];
  __shared__ ushort Ws_lo[SPLITW ? 64 : 1][SPLITW ? 128 : 1];
  int tid = threadIdx.x;
  int row0 = blockIdx.y * 64, col0 = blockIdx.x * 64;
  int w = tid >> 6, lane = tid & 63;
  int wr = w >> 1, wc = w & 1;
  f32x4 acc[2][2] = {};
  int nk = K >> 7;
  for (int kc = 0; kc < nk; ++kc) {
    int k0 = kc << 7;
    if (kc) __syncthreads();
#pragma unroll
    for (int i = 0; i < 4; ++i) {
      int f = i * 256 + tid;
      int r = f >> 4, c8 = (f & 15) * 8;
      int ksw = c8 ^ ((r & 7) << 3);
      if (row0 + r < M) {
        if (A_FP32) {
          const float* Af = (const float*)A;
          float4 v0 = *(const float4*)&Af[(size_t)(row0 + r) * K + k0 + c8];
          float4 v1 = *(const float4*)&Af[(size_t)(row0 + r) * K + k0 + c8 + 4];
          ushort4 h0, h1;
          h0.x = bf_rne(v0.x); h0.y = bf_rne(v0.y); h0.z = bf_rne(v0.z); h0.w = bf_rne(v0.w);
          h1.x = bf_rne(v1.x); h1.y = bf_rne(v1.y); h1.z = bf_rne(v1.z); h1.w = bf_rne(v1.w);
          *(ushort4*)&As[r][ksw] = h0;
          *(ushort4*)&As[r][ksw + 4] = h1;
        } else {
          const ushort* Ab = (const ushort*)A;
          *(bf16x8*)&As[r][ksw] = *(const bf16x8*)&Ab[(size_t)(row0 + r) * K + k0 + c8];
        }
      } else {
        ushort4 z = {0, 0, 0, 0};
        *(ushort4*)&As[r][ksw] = z;
        *(ushort4*)&As[r][ksw + 4] = z;
      }
    }
#pragma unroll
    for (int i = 0; i < 4; ++i) {
      int f = i * 256 + tid;
      int r = f >> 4, c8 = (f & 15) * 8;
      int ksw = c8 ^ ((r & 7) << 3);
      *(bf16x8*)&Ws_hi[r][ksw] = *(const bf16x8*)&Wt_hi[(size_t)(col0 + r) * K + k0 + c8];
      if (SPLITW)
        *(bf16x8*)&Ws_lo[r][ksw] = *(const bf16x8*)&Wt_lo[(size_t)(col0 + r) * K + k0 + c8];
    }
    __syncthreads();
#pragma unroll
    for (int ks = 0; ks < 4; ++ks) {
      int kk = ks * 32 + (lane >> 4) * 8;
      bf16x8 a[2], bh[2], bl[2];
#pragma unroll
      for (int m = 0; m < 2; ++m) {
        int r = wr * 32 + m * 16 + (lane & 15);
        a[m] = *(bf16x8*)&As[r][kk ^ ((r & 7) << 3)];
      }
#pragma unroll
      for (int n = 0; n < 2; ++n) {
        int r = wc * 32 + n * 16 + (lane & 15);
        int ksw = kk ^ ((r & 7) << 3);
        bh[n] = *(bf16x8*)&Ws_hi[r][ksw];
        if (SPLITW) bl[n] = *(bf16x8*)&Ws_lo[r][ksw];
      }
#pragma unroll
      for (int m = 0; m < 2; ++m)
#pragma unroll
        for (int n = 0; n < 2; ++n) {
          acc[m][n] = __builtin_amdgcn_mfma_f32_16x16x32_bf16(a[m], bh[n], acc[m][n], 0, 0, 0);
          if (SPLITW)
            acc[m][n] = __builtin_amdgcn_mfma_f32_16x16x32_bf16(a[m], bl[n], acc[m][n], 0, 0, 0);
        }
    }
  }
#pragma unroll
  for (int m = 0; m < 2; ++m) {
    int rbase = row0 + wr * 32 + m * 16 + (lane >> 4) * 4;
#pragma unroll
    for (int n = 0; n < 2; ++n) {
      int col = col0 + wc * 32 + n * 16 + (lane & 15);
      float b = bias[col];
#pragma unroll
      for (int r = 0; r < 4; ++r) {
        int row = rbase + r;
        if (row < M) {
          float v = acc[m][n][r] + b;
          if (RELU) v = fmaxf(v, 0.f);
          if (OUT_BF16)
            ((ushort*)Cout)[(size_t)row * N + col] = bf_rne(v);
          else
            ((float*)Cout)[(size_t)row * N + col] = v;
        }
      }
    }
  }
}

// ---- slot-0 pool: per-graph sum of fp32 x (sole writer, no atomics) -------
__global__ __launch_bounds__(128) void k_pool0(const float* __restrict__ x,
                                               const int* __restrict__ batch,
                                               float* __restrict__ pgf, int N, int F) {
  int g = blockIdx.x;
  int d = threadIdx.x;
  int lo = 0, hi = N;
  while (lo < hi) {
    int mid = (lo + hi) >> 1;
    if (batch[mid] < g) lo = mid + 1; else hi = mid;
  }
  int s = lo;
  hi = N;
  while (lo < hi) {
    int mid = (lo + hi) >> 1;
    if (batch[mid] < g + 1) lo = mid + 1; else hi = mid;
  }
  int e = lo;
  float acc = 0.f;
  for (int v = s; v < e; ++v) acc += x[(size_t)v * 128 + d];
  pgf[(size_t)g * F + d] = acc;
}

// ---- lin2 (768 -> C) + softmax, one wave per graph ------------------------
__global__ __launch_bounds__(64) void k_lin2_softmax(const float* __restrict__ A,
                                                     const float* __restrict__ W,
                                                     const float* __restrict__ b,
                                                     float* __restrict__ out, int K, int C) {
  constexpr int CMAX = 16;
  int g = blockIdx.x;
  int lane = threadIdx.x;
  float acc[CMAX];
#pragma unroll
  for (int c = 0; c < CMAX; ++c) acc[c] = 0.f;
  for (int k = lane; k < K; k += 64) {
    float a = A[(size_t)g * K + k];
#pragma unroll
    for (int c = 0; c < CMAX; ++c)
      if (c < C) acc[c] = fmaf(a, W[(size_t)k * C + c], acc[c]);
  }
#pragma unroll
  for (int off = 32; off; off >>= 1)
#pragma unroll
    for (int c = 0; c < CMAX; ++c) acc[c] += __shfl_xor(acc[c], off, 64);
  if (lane == 0) {
    float mx = -3.0e38f;
#pragma unroll
    for (int c = 0; c < CMAX; ++c)
      if (c < C) {
        acc[c] += b[c];
        mx = fmaxf(mx, acc[c]);
      }
    float sum = 0.f;
#pragma unroll
    for (int c = 0; c < CMAX; ++c)
      if (c < C) {
        acc[c] = expf(acc[c] - mx);
        sum += acc[c];
      }
    float inv = 1.f / sum;
#pragma unroll
    for (int c = 0; c < CMAX; ++c)
      if (c < C) out[(size_t)g * C + c] = acc[c] * inv;
  }
}

// ---------------------------------------------------------------------------
extern "C" void kernel_launch(void* const* d_in, const int* in_sizes, int n_in,
                              void* d_out, int out_size, void* d_ws, size_t ws_size,
                              hipStream_t stream) {
  const float* x     = (const float*)d_in[0];
  const int*   eidx  = (const int*)d_in[1];
  const float* emask = (const float*)d_in[2];
  const int*   batch = (const int*)d_in[3];
  const float* eps   = (const float*)d_in[5];
  const float* w1    = (const float*)d_in[6];
  const float* b1    = (const float*)d_in[7];
  const float* w2    = (const float*)d_in[8];
  const float* b2    = (const float*)d_in[9];
  const float* l1w   = (const float*)d_in[10];
  const float* l1b   = (const float*)d_in[11];
  const float* l2w   = (const float*)d_in[12];
  const float* l2b   = (const float*)d_in[13];

  const int N = in_sizes[3];          // 50000
  const int E = in_sizes[2];          // 800000
  const int L = in_sizes[5];          // 5
  const int D = in_sizes[0] / N;      // 128
  const int C = in_sizes[13];         // 10
  const int G = out_size / C;         // 512
  const int L1 = L + 1;
  const int H = in_sizes[7] / L;      // 128
  const int F = L1 * D;               // 768

  const int* src = eidx;
  const int* dst = eidx + E;

  // workspace carve (256B aligned)
  char* p = (char*)d_ws;
  auto carve = [&](size_t bytes) -> void* {
    void* r = (void*)p;
    p += (bytes + 255) & ~(size_t)255;
    return r;
  };
  int*    rowptr = (int*)carve((size_t)(N + 1) * 4);
  int*    cursor = (int*)carve((size_t)N * 4);
  int*    deg    = (int*)carve((size_t)N * 4);
  int*    excl   = (int*)carve((size_t)N * 4);
  int*    bsum   = (int*)carve(256 * 4);
  int*    boff   = (int*)carve(256 * 4);
  int2*   sedge  = (int2*)carve((size_t)E * 8);
  ushort* xb     = (ushort*)carve((size_t)N * D * 2);
  ushort* pooled = (ushort*)carve((size_t)N * D * 2);
  ushort* hb[5];
  for (int l = 0; l < 5; ++l) hb[l] = (ushort*)carve((size_t)N * D * 2);
  float*  pgf    = (float*)carve((size_t)G * F * 4);
  float*  l1out  = (float*)carve((size_t)G * F * 4);
  ushort* w1t_hi = (ushort*)carve((size_t)L * D * H * 2);
  ushort* w2t_hi = (ushort*)carve((size_t)L * H * D * 2);
  ushort* l1t_hi = (ushort*)carve((size_t)F * F * 2);
  ushort* l1t_lo = (ushort*)carve((size_t)F * F * 2);
  (void)ws_size;

  // CSR build (once; adjacency is layer-invariant)
  const int nb = ceil_div(N, 1024);
  hipMemsetAsync(deg, 0, (size_t)N * 4, stream);
  hipMemsetAsync(pgf, 0, (size_t)G * F * 4, stream);
  k_hist<<<ceil_div(E, 256), 256, 0, stream>>>(src, deg, E);
  k_scan1<<<nb, 256, 0, stream>>>(deg, excl, bsum, N);
  k_scan2<<<1, 256, 0, stream>>>(bsum, boff, nb, &rowptr[N]);
  k_scan3<<<ceil_div(N, 256), 256, 0, stream>>>(excl, boff, rowptr, cursor, N);
  k_scatter<<<ceil_div(E, 256), 256, 0, stream>>>(src, dst, emask, cursor, sedge, E);

  // x -> bf16; weight prep
  k_tobf16<<<ceil_div(N * D, 1024), 256, 0, stream>>>(x, xb, N * D);
  k_prepw12<<<dim3(4, 4, 2 * L), 256, 0, stream>>>(w1, w2, w1t_hi, w2t_hi, L);
  k_prepw<<<dim3(F / 32, F / 32), 256, 0, stream>>>(l1w, l1t_hi, l1t_lo, F, F);

  // slot 0: pool fp32 x directly
  k_pool0<<<G, 128, 0, stream>>>(x, batch, pgf, N, F);

  const ushort* h_in = xb;
  for (int l = 0; l < L; ++l) {
    k_agg<<<ceil_div(N, 2), 128, 0, stream>>>(h_in, rowptr, sedge, eps, l, pooled, N);
    k_mlp<<<ceil_div(N, 64), 256, 0, stream>>>(
        pooled, w1t_hi + (size_t)l * D * H, b1 + (size_t)l * H,
        w2t_hi + (size_t)l * H * D, b2 + (size_t)l * D, hb[l],
        batch, pgf, (l + 1) * 128, F, N);
    h_in = hb[l];
  }

  // classifier: lin1 (relu, K=768, split W, fp32 A), lin2 + softmax
  k_mgemm<1, 0, 1, 1><<<dim3(F / 64, ceil_div(G, 64)), 256, 0, stream>>>(
      pgf, l1t_hi, l1t_lo, l1b, l1out, G, F, F);
  k_lin2_softmax<<<G, 64, 0, stream>>>(l1out, l2w, l2b, (float*)d_out, F, C);
}

// Round 9
// 421.861 us; speedup vs baseline: 1.5096x; 1.5096x over previous
//
#include <hip/hip_runtime.h>

// ---------------------------------------------------------------------------
// GIN model. R9 = R7 revert (R8's atomic pool-fusion cost 5x in k_mlp) plus:
//  - k_prepw12 merged weight prep (kept from R8)
//  - k_scan2 folded into k_scan3 (redundant 49-elem LDS scan per block)
//  - k_agg 16-deep gather unroll (probe: latency- vs fabric-bound)
//  - k_mlp: A-fragments direct from global (no As LDS stage) -> 48KB LDS,
//    3 blocks/CU
// Numerics unchanged: bf16 activations, RNE bf16 MLP W, split-bf16 lin1 W.
// ---------------------------------------------------------------------------

typedef __bf16 bf16x8 __attribute__((ext_vector_type(8)));
typedef float f32x4 __attribute__((ext_vector_type(4)));

static inline int ceil_div(int a, int b) { return (a + b - 1) / b; }

__device__ inline ushort bf_rne(float v) {
  unsigned u = __float_as_uint(v);
  return (ushort)((u + 0x7fffu + ((u >> 16) & 1u)) >> 16);
}
__device__ inline float bf2f(ushort u) { return __uint_as_float((unsigned)u << 16); }
__device__ inline float bf2f_lo(unsigned g) { return __uint_as_float(g << 16); }
__device__ inline float bf2f_hi(unsigned g) { return __uint_as_float(g & 0xffff0000u); }

// ---- CSR build ------------------------------------------------------------
__global__ void k_hist(const int* __restrict__ src, int* __restrict__ deg, int E) {
  int i = blockIdx.x * blockDim.x + threadIdx.x;
  if (i < E) atomicAdd(&deg[src[i]], 1);
}

__global__ __launch_bounds__(256) void k_scan1(const int* __restrict__ deg,
                                               int* __restrict__ excl,
                                               int* __restrict__ bsum, int N) {
  __shared__ int tsum[256];
  int b = blockIdx.x, t = threadIdx.x;
  int base = b * 1024 + t * 4;
  int v0 = 0, v1 = 0, v2 = 0, v3 = 0;
  if (base + 3 < N) {
    int4 q = *(const int4*)&deg[base];
    v0 = q.x; v1 = q.y; v2 = q.z; v3 = q.w;
  } else {
    if (base + 0 < N) v0 = deg[base + 0];
    if (base + 1 < N) v1 = deg[base + 1];
    if (base + 2 < N) v2 = deg[base + 2];
    if (base + 3 < N) v3 = deg[base + 3];
  }
  tsum[t] = v0 + v1 + v2 + v3;
  __syncthreads();
  for (int off = 1; off < 256; off <<= 1) {
    int x = (t >= off) ? tsum[t - off] : 0;
    __syncthreads();
    tsum[t] += x;
    __syncthreads();
  }
  int pre = (t == 0) ? 0 : tsum[t - 1];
  if (base < N)     excl[base]     = pre;
  if (base + 1 < N) excl[base + 1] = pre + v0;
  if (base + 2 < N) excl[base + 2] = pre + v0 + v1;
  if (base + 3 < N) excl[base + 3] = pre + v0 + v1 + v2;
  if (t == 255) bsum[b] = tsum[255];
}

// merged: scans bsum (nb<=256) in LDS per block, then applies offsets
__global__ __launch_bounds__(256) void k_scan3(const int* __restrict__ excl,
                                               const int* __restrict__ bsum, int nb,
                                               int* __restrict__ rowptr,
                                               int* __restrict__ cursor, int N) {
  __shared__ int s[256];
  int t = threadIdx.x;
  s[t] = (t < nb) ? bsum[t] : 0;
  __syncthreads();
  for (int off = 1; off < 256; off <<= 1) {
    int x = (t >= off) ? s[t - off] : 0;
    __syncthreads();
    s[t] += x;
    __syncthreads();
  }
  int i = blockIdx.x * 256 + t;
  if (i < N) {
    int blk = i >> 10;
    int boff = blk ? s[blk - 1] : 0;
    int v = excl[i] + boff;
    rowptr[i] = v;
    cursor[i] = v;
  }
  if (i == N - 1) rowptr[N] = s[nb - 1];
}

__global__ void k_scatter(const int* __restrict__ src, const int* __restrict__ dst,
                          const float* __restrict__ mask, int* __restrict__ cursor,
                          int2* __restrict__ sedge, int E) {
  int i = blockIdx.x * blockDim.x + threadIdx.x;
  if (i < E) {
    int s = src[i];
    int p = atomicAdd(&cursor[s], 1);
    sedge[p] = make_int2(dst[i], __float_as_int(mask[i]));
  }
}

// ---- fp32 -> bf16 conversion ---------------------------------------------
__global__ __launch_bounds__(256) void k_tobf16(const float* __restrict__ in,
                                                ushort* __restrict__ out, int n) {
  int base = (blockIdx.x * 256 + threadIdx.x) * 4;
  if (base + 3 < n) {
    float4 v = *(const float4*)&in[base];
    ushort4 o;
    o.x = bf_rne(v.x); o.y = bf_rne(v.y); o.z = bf_rne(v.z); o.w = bf_rne(v.w);
    *(ushort4*)&out[base] = o;
  } else {
    for (int k = base; k < n; ++k) out[k] = bf_rne(in[k]);
  }
}

// ---- weight prep: both MLP weight sets in one dispatch --------------------
__global__ __launch_bounds__(256) void k_prepw12(const float* __restrict__ W1,
                                                 const float* __restrict__ W2,
                                                 ushort* __restrict__ hi1,
                                                 ushort* __restrict__ hi2, int L) {
  __shared__ float t[32][33];
  int z = blockIdx.z;
  const float* Wm = (z < L) ? (W1 + (size_t)z * 128 * 128)
                            : (W2 + (size_t)(z - L) * 128 * 128);
  ushort* him = (z < L) ? (hi1 + (size_t)z * 128 * 128)
                        : (hi2 + (size_t)(z - L) * 128 * 128);
  int k0 = blockIdx.x * 32, n0 = blockIdx.y * 32;
  int tx = threadIdx.x & 31, ty = threadIdx.x >> 5;
#pragma unroll
  for (int r = 0; r < 32; r += 8)
    t[ty + r][tx] = Wm[(size_t)(k0 + ty + r) * 128 + n0 + tx];
  __syncthreads();
#pragma unroll
  for (int r = 0; r < 32; r += 8) {
    float v = t[tx][ty + r];
    him[(size_t)(n0 + ty + r) * 128 + k0 + tx] = bf_rne(v);
  }
}

// ---- weight prep for lin1: split hi/lo, transposed ------------------------
__global__ __launch_bounds__(256) void k_prepw(const float* __restrict__ W,
                                               ushort* __restrict__ hi,
                                               ushort* __restrict__ lo,
                                               int K, int N) {
  __shared__ float t[32][33];
  int k0 = blockIdx.x * 32, n0 = blockIdx.y * 32;
  int tx = threadIdx.x & 31, ty = threadIdx.x >> 5;
#pragma unroll
  for (int r = 0; r < 32; r += 8)
    t[ty + r][tx] = W[(size_t)(k0 + ty + r) * N + n0 + tx];
  __syncthreads();
#pragma unroll
  for (int r = 0; r < 32; r += 8) {
    float v = t[tx][ty + r];
    size_t o = (size_t)(n0 + ty + r) * K + k0 + tx;
    ushort h = bf_rne(v);
    hi[o] = h;
    lo[o] = bf_rne(v - bf2f(h));
  }
}

// ---- per-node aggregation: 1 wave per node, 16-deep gather unroll ---------
__global__ __launch_bounds__(128) void k_agg(const ushort* __restrict__ h,
                                             const int* __restrict__ rowptr,
                                             const int2* __restrict__ sedge,
                                             const float* __restrict__ eps, int layer,
                                             ushort* __restrict__ pooled, int N) {
  int v = blockIdx.x * 2 + (threadIdx.x >> 6);
  int lane = threadIdx.x & 63;
  if (v >= N) return;
  int beg = rowptr[v], end = rowptr[v + 1];
  float ax[8] = {}, ay[8] = {};
  int j = beg;
  for (; j + 16 <= end; j += 16) {
    int2 e[16];
    unsigned g[16];
#pragma unroll
    for (int q = 0; q < 16; ++q) e[q] = sedge[j + q];
#pragma unroll
    for (int q = 0; q < 16; ++q)
      g[q] = *(const unsigned*)&h[(size_t)e[q].x * 128 + lane * 2];
#pragma unroll
    for (int q = 0; q < 16; ++q) {
      float m = __int_as_float(e[q].y);
      ax[q & 7] = fmaf(m, bf2f_lo(g[q]), ax[q & 7]);
      ay[q & 7] = fmaf(m, bf2f_hi(g[q]), ay[q & 7]);
    }
  }
  for (; j + 8 <= end; j += 8) {
    int2 e[8];
    unsigned g[8];
#pragma unroll
    for (int q = 0; q < 8; ++q) e[q] = sedge[j + q];
#pragma unroll
    for (int q = 0; q < 8; ++q)
      g[q] = *(const unsigned*)&h[(size_t)e[q].x * 128 + lane * 2];
#pragma unroll
    for (int q = 0; q < 8; ++q) {
      float m = __int_as_float(e[q].y);
      ax[q] = fmaf(m, bf2f_lo(g[q]), ax[q]);
      ay[q] = fmaf(m, bf2f_hi(g[q]), ay[q]);
    }
  }
  for (; j + 2 <= end; j += 2) {
    int2 e0 = sedge[j], e1 = sedge[j + 1];
    unsigned g0 = *(const unsigned*)&h[(size_t)e0.x * 128 + lane * 2];
    unsigned g1 = *(const unsigned*)&h[(size_t)e1.x * 128 + lane * 2];
    ax[0] = fmaf(__int_as_float(e0.y), bf2f_lo(g0), ax[0]);
    ay[0] = fmaf(__int_as_float(e0.y), bf2f_hi(g0), ay[0]);
    ax[1] = fmaf(__int_as_float(e1.y), bf2f_lo(g1), ax[1]);
    ay[1] = fmaf(__int_as_float(e1.y), bf2f_hi(g1), ay[1]);
  }
  if (j < end) {
    int2 e = sedge[j];
    unsigned g = *(const unsigned*)&h[(size_t)e.x * 128 + lane * 2];
    float m = __int_as_float(e.y);
    ax[0] = fmaf(m, bf2f_lo(g), ax[0]);
    ay[0] = fmaf(m, bf2f_hi(g), ay[0]);
  }
  float sx = ((ax[0] + ax[1]) + (ax[2] + ax[3])) + ((ax[4] + ax[5]) + (ax[6] + ax[7]));
  float sy = ((ay[0] + ay[1]) + (ay[2] + ay[3])) + ((ay[4] + ay[5]) + (ay[6] + ay[7]));
  float ep = 1.0f + eps[layer];
  unsigned gs = *(const unsigned*)&h[(size_t)v * 128 + lane * 2];
  sx = fmaf(ep, bf2f_lo(gs), sx);
  sy = fmaf(ep, bf2f_hi(gs), sy);
  unsigned outw = (unsigned)bf_rne(sx) | ((unsigned)bf_rne(sy) << 16);
  *(unsigned*)&pooled[(size_t)v * 128 + lane * 2] = outw;
}

// ---- fused 2-layer MLP: h_out = relu(relu(pooled@W1+b1)@W2+b2) ------------
// A-fragments direct from global (16KB tile, L1-hot). LDS: Ws 32K + H1s 16K
// = 48KB -> 3 blocks/CU.
__global__ __launch_bounds__(256) void k_mlp(
    const ushort* __restrict__ pooled,
    const ushort* __restrict__ w1t, const float* __restrict__ b1,
    const ushort* __restrict__ w2t, const float* __restrict__ b2,
    ushort* __restrict__ hout, int N) {
  __shared__ ushort Ws[128][128];
  __shared__ ushort H1s[64][128];
  int tid = threadIdx.x;
  int w = tid >> 6, lane = tid & 63;
  int row0 = blockIdx.x * 64;
  int wr = w >> 1, wc = w & 1;

  // stage W1
#pragma unroll
  for (int i = 0; i < 8; ++i) {
    int f = i * 256 + tid;
    int r = f >> 4, c8 = (f & 15) * 8;
    *(bf16x8*)&Ws[r][c8 ^ ((r & 7) << 3)] = *(const bf16x8*)&w1t[(size_t)r * 128 + c8];
  }
  __syncthreads();

  // GEMM1: waves 2x2, each 32 rows x 64 cols; A direct from global
  f32x4 acc[2][4];
#pragma unroll
  for (int m = 0; m < 2; ++m)
#pragma unroll
    for (int n = 0; n < 4; ++n) acc[m][n] = (f32x4){0.f, 0.f, 0.f, 0.f};
#pragma unroll
  for (int ks = 0; ks < 4; ++ks) {
    int kk = ks * 32 + (lane >> 4) * 8;
    bf16x8 a[2], b[4];
#pragma unroll
    for (int m = 0; m < 2; ++m) {
      int arow = row0 + wr * 32 + m * 16 + (lane & 15);
      if (arow >= N) arow = N - 1;
      a[m] = *(const bf16x8*)&pooled[(size_t)arow * 128 + kk];
    }
#pragma unroll
    for (int n = 0; n < 4; ++n) {
      int r = wc * 64 + n * 16 + (lane & 15);
      b[n] = *(bf16x8*)&Ws[r][kk ^ ((r & 7) << 3)];
    }
#pragma unroll
    for (int m = 0; m < 2; ++m)
#pragma unroll
      for (int n = 0; n < 4; ++n)
        acc[m][n] = __builtin_amdgcn_mfma_f32_16x16x32_bf16(a[m], b[n], acc[m][n], 0, 0, 0);
  }
#pragma unroll
  for (int m = 0; m < 2; ++m) {
    int rbase = wr * 32 + m * 16 + (lane >> 4) * 4;
#pragma unroll
    for (int n = 0; n < 4; ++n) {
      int col = wc * 64 + n * 16 + (lane & 15);
      float bb = b1[col];
#pragma unroll
      for (int r = 0; r < 4; ++r) {
        int row = rbase + r;
        float v = fmaxf(acc[m][n][r] + bb, 0.f);
        H1s[row][col ^ ((row & 7) << 3)] = bf_rne(v);
      }
    }
  }
  __syncthreads();

  // restage W2 over Ws
#pragma unroll
  for (int i = 0; i < 8; ++i) {
    int f = i * 256 + tid;
    int r = f >> 4, c8 = (f & 15) * 8;
    *(bf16x8*)&Ws[r][c8 ^ ((r & 7) << 3)] = *(const bf16x8*)&w2t[(size_t)r * 128 + c8];
  }
  __syncthreads();

  // GEMM2
#pragma unroll
  for (int m = 0; m < 2; ++m)
#pragma unroll
    for (int n = 0; n < 4; ++n) acc[m][n] = (f32x4){0.f, 0.f, 0.f, 0.f};
#pragma unroll
  for (int ks = 0; ks < 4; ++ks) {
    int kk = ks * 32 + (lane >> 4) * 8;
    bf16x8 a[2], b[4];
#pragma unroll
    for (int m = 0; m < 2; ++m) {
      int r = wr * 32 + m * 16 + (lane & 15);
      a[m] = *(bf16x8*)&H1s[r][kk ^ ((r & 7) << 3)];
    }
#pragma unroll
    for (int n = 0; n < 4; ++n) {
      int r = wc * 64 + n * 16 + (lane & 15);
      b[n] = *(bf16x8*)&Ws[r][kk ^ ((r & 7) << 3)];
    }
#pragma unroll
    for (int m = 0; m < 2; ++m)
#pragma unroll
      for (int n = 0; n < 4; ++n)
        acc[m][n] = __builtin_amdgcn_mfma_f32_16x16x32_bf16(a[m], b[n], acc[m][n], 0, 0, 0);
  }
#pragma unroll
  for (int m = 0; m < 2; ++m) {
    int rbase = row0 + wr * 32 + m * 16 + (lane >> 4) * 4;
#pragma unroll
    for (int n = 0; n < 4; ++n) {
      int col = wc * 64 + n * 16 + (lane & 15);
      float bb = b2[col];
#pragma unroll
      for (int r = 0; r < 4; ++r) {
        int row = rbase + r;
        if (row < N) {
          float v = fmaxf(acc[m][n][r] + bb, 0.f);
          hout[(size_t)row * 128 + col] = bf_rne(v);
        }
      }
    }
  }
}

// ---- bf16-A MFMA GEMM (classifier lin1): split W --------------------------
template <int RELU, int OUT_BF16, int SPLITW>
__global__ __launch_bounds__(256) void k_mgemm(const ushort* __restrict__ A,
                                               const ushort* __restrict__ Wt_hi,
                                               const ushort* __restrict__ Wt_lo,
                                               const float* __restrict__ bias,
                                               void* __restrict__ Cout,
                                               int M, int N, int K) {
  __shared__ ushort As[64][128];
  __shared__ ushort Ws_hi[64][128];
  __shared__ ushort Ws_lo[SPLITW ? 64 : 1][SPLITW ? 128 : 1];
  int tid = threadIdx.x;
  int row0 = blockIdx.y * 64, col0 = blockIdx.x * 64;
  int w = tid >> 6, lane = tid & 63;
  int wr = w >> 1, wc = w & 1;
  f32x4 acc[2][2] = {};
  int nk = K >> 7;
  for (int kc = 0; kc < nk; ++kc) {
    int k0 = kc << 7;
    if (kc) __syncthreads();
#pragma unroll
    for (int i = 0; i < 4; ++i) {
      int f = i * 256 + tid;
      int r = f >> 4, c8 = (f & 15) * 8;
      int ksw = c8 ^ ((r & 7) << 3);
      if (row0 + r < M) {
        *(bf16x8*)&As[r][ksw] = *(const bf16x8*)&A[(size_t)(row0 + r) * K + k0 + c8];
      } else {
        ushort4 z = {0, 0, 0, 0};
        *(ushort4*)&As[r][ksw] = z;
        *(ushort4*)&As[r][ksw + 4] = z;
      }
    }
#pragma unroll
    for (int i = 0; i < 4; ++i) {
      int f = i * 256 + tid;
      int r = f >> 4, c8 = (f & 15) * 8;
      int ksw = c8 ^ ((r & 7) << 3);
      *(bf16x8*)&Ws_hi[r][ksw] = *(const bf16x8*)&Wt_hi[(size_t)(col0 + r) * K + k0 + c8];
      if (SPLITW)
        *(bf16x8*)&Ws_lo[r][ksw] = *(const bf16x8*)&Wt_lo[(size_t)(col0 + r) * K + k0 + c8];
    }
    __syncthreads();
#pragma unroll
    for (int ks = 0; ks < 4; ++ks) {
      int kk = ks * 32 + (lane >> 4) * 8;
      bf16x8 a[2], bh[2], bl[2];
#pragma unroll
      for (int m = 0; m < 2; ++m) {
        int r = wr * 32 + m * 16 + (lane & 15);
        a[m] = *(bf16x8*)&As[r][kk ^ ((r & 7) << 3)];
      }
#pragma unroll
      for (int n = 0; n < 2; ++n) {
        int r = wc * 32 + n * 16 + (lane & 15);
        int ksw = kk ^ ((r & 7) << 3);
        bh[n] = *(bf16x8*)&Ws_hi[r][ksw];
        if (SPLITW) bl[n] = *(bf16x8*)&Ws_lo[r][ksw];
      }
#pragma unroll
      for (int m = 0; m < 2; ++m)
#pragma unroll
        for (int n = 0; n < 2; ++n) {
          acc[m][n] = __builtin_amdgcn_mfma_f32_16x16x32_bf16(a[m], bh[n], acc[m][n], 0, 0, 0);
          if (SPLITW)
            acc[m][n] = __builtin_amdgcn_mfma_f32_16x16x32_bf16(a[m], bl[n], acc[m][n], 0, 0, 0);
        }
    }
  }
#pragma unroll
  for (int m = 0; m < 2; ++m) {
    int rbase = row0 + wr * 32 + m * 16 + (lane >> 4) * 4;
#pragma unroll
    for (int n = 0; n < 2; ++n) {
      int col = col0 + wc * 32 + n * 16 + (lane & 15);
      float b = bias[col];
#pragma unroll
      for (int r = 0; r < 4; ++r) {
        int row = rbase + r;
        if (row < M) {
          float v = acc[m][n][r] + b;
          if (RELU) v = fmaxf(v, 0.f);
          if (OUT_BF16)
            ((ushort*)Cout)[(size_t)row * N + col] = bf_rne(v);
          else
            ((float*)Cout)[(size_t)row * N + col] = v;
        }
      }
    }
  }
}

// ---- batched per-graph pooling: all 6 slots in one dispatch ---------------
__global__ __launch_bounds__(128) void k_pool_all(
    const ushort* __restrict__ f0, const ushort* __restrict__ f1,
    const ushort* __restrict__ f2, const ushort* __restrict__ f3,
    const ushort* __restrict__ f4, const ushort* __restrict__ f5,
    const int* __restrict__ batch, ushort* __restrict__ pg, int N, int L1) {
  __shared__ float red[2][64][2];
  int g = blockIdx.x;
  int slot = blockIdx.y;
  const ushort* feat;
  switch (slot) {
    case 0: feat = f0; break;
    case 1: feat = f1; break;
    case 2: feat = f2; break;
    case 3: feat = f3; break;
    case 4: feat = f4; break;
    default: feat = f5; break;
  }
  int w = threadIdx.x >> 6, lane = threadIdx.x & 63;
  int lo = 0, hi = N;
  while (lo < hi) {
    int mid = (lo + hi) >> 1;
    if (batch[mid] < g) lo = mid + 1; else hi = mid;
  }
  int s = lo;
  hi = N;
  while (lo < hi) {
    int mid = (lo + hi) >> 1;
    if (batch[mid] < g + 1) lo = mid + 1; else hi = mid;
  }
  int e = lo;
  float a0 = 0.f, a1 = 0.f;
#pragma unroll 4
  for (int v = s + w; v < e; v += 2) {
    unsigned u = *(const unsigned*)&feat[(size_t)v * 128 + lane * 2];
    a0 += bf2f_lo(u);
    a1 += bf2f_hi(u);
  }
  red[w][lane][0] = a0;
  red[w][lane][1] = a1;
  __syncthreads();
  if (w == 0) {
    a0 = red[0][lane][0] + red[1][lane][0];
    a1 = red[0][lane][1] + red[1][lane][1];
    unsigned outw = (unsigned)bf_rne(a0) | ((unsigned)bf_rne(a1) << 16);
    *(unsigned*)&pg[((size_t)g * L1 + slot) * 128 + lane * 2] = outw;
  }
}

// ---- lin2 (768 -> C) + softmax, one wave per graph ------------------------
__global__ __launch_bounds__(64) void k_lin2_softmax(const float* __restrict__ A,
                                                     const float* __restrict__ W,
                                                     const float* __restrict__ b,
                                                     float* __restrict__ out, int K, int C) {
  constexpr int CMAX = 16;
  int g = blockIdx.x;
  int lane = threadIdx.x;
  float acc[CMAX];
#pragma unroll
  for (int c = 0; c < CMAX; ++c) acc[c] = 0.f;
  for (int k = lane; k < K; k += 64) {
    float a = A[(size_t)g * K + k];
#pragma unroll
    for (int c = 0; c < CMAX; ++c)
      if (c < C) acc[c] = fmaf(a, W[(size_t)k * C + c], acc[c]);
  }
#pragma unroll
  for (int off = 32; off; off >>= 1)
#pragma unroll
    for (int c = 0; c < CMAX; ++c) acc[c] += __shfl_xor(acc[c], off, 64);
  if (lane == 0) {
    float mx = -3.0e38f;
#pragma unroll
    for (int c = 0; c < CMAX; ++c)
      if (c < C) {
        acc[c] += b[c];
        mx = fmaxf(mx, acc[c]);
      }
    float sum = 0.f;
#pragma unroll
    for (int c = 0; c < CMAX; ++c)
      if (c < C) {
        acc[c] = expf(acc[c] - mx);
        sum += acc[c];
      }
    float inv = 1.f / sum;
#pragma unroll
    for (int c = 0; c < CMAX; ++c)
      if (c < C) out[(size_t)g * C + c] = acc[c] * inv;
  }
}

// ---------------------------------------------------------------------------
extern "C" void kernel_launch(void* const* d_in, const int* in_sizes, int n_in,
                              void* d_out, int out_size, void* d_ws, size_t ws_size,
                              hipStream_t stream) {
  const float* x     = (const float*)d_in[0];
  const int*   eidx  = (const int*)d_in[1];
  const float* emask = (const float*)d_in[2];
  const int*   batch = (const int*)d_in[3];
  const float* eps   = (const float*)d_in[5];
  const float* w1    = (const float*)d_in[6];
  const float* b1    = (const float*)d_in[7];
  const float* w2    = (const float*)d_in[8];
  const float* b2    = (const float*)d_in[9];
  const float* l1w   = (const float*)d_in[10];
  const float* l1b   = (const float*)d_in[11];
  const float* l2w   = (const float*)d_in[12];
  const float* l2b   = (const float*)d_in[13];

  const int N = in_sizes[3];          // 50000
  const int E = in_sizes[2];          // 800000
  const int L = in_sizes[5];          // 5
  const int D = in_sizes[0] / N;      // 128
  const int C = in_sizes[13];         // 10
  const int G = out_size / C;         // 512
  const int L1 = L + 1;
  const int H = in_sizes[7] / L;      // 128
  const int F = L1 * D;               // 768

  const int* src = eidx;
  const int* dst = eidx + E;

  // workspace carve (256B aligned)
  char* p = (char*)d_ws;
  auto carve = [&](size_t bytes) -> void* {
    void* r = (void*)p;
    p += (bytes + 255) & ~(size_t)255;
    return r;
  };
  int*    rowptr = (int*)carve((size_t)(N + 1) * 4);
  int*    cursor = (int*)carve((size_t)N * 4);
  int*    deg    = (int*)carve((size_t)N * 4);
  int*    excl   = (int*)carve((size_t)N * 4);
  int*    bsum   = (int*)carve(256 * 4);
  int2*   sedge  = (int2*)carve((size_t)E * 8);
  ushort* xb     = (ushort*)carve((size_t)N * D * 2);
  ushort* pooled = (ushort*)carve((size_t)N * D * 2);
  ushort* hb[5];
  for (int l = 0; l < 5; ++l) hb[l] = (ushort*)carve((size_t)N * D * 2);
  ushort* pg     = (ushort*)carve((size_t)G * F * 2);
  float*  l1out  = (float*)carve((size_t)G * F * 4);
  ushort* w1t_hi = (ushort*)carve((size_t)L * D * H * 2);
  ushort* w2t_hi = (ushort*)carve((size_t)L * H * D * 2);
  ushort* l1t_hi = (ushort*)carve((size_t)F * F * 2);
  ushort* l1t_lo = (ushort*)carve((size_t)F * F * 2);
  (void)ws_size;

  // CSR build (once; adjacency is layer-invariant)
  const int nb = ceil_div(N, 1024);
  hipMemsetAsync(deg, 0, (size_t)N * 4, stream);
  k_hist<<<ceil_div(E, 256), 256, 0, stream>>>(src, deg, E);
  k_scan1<<<nb, 256, 0, stream>>>(deg, excl, bsum, N);
  k_scan3<<<ceil_div(N, 256), 256, 0, stream>>>(excl, bsum, nb, rowptr, cursor, N);
  k_scatter<<<ceil_div(E, 256), 256, 0, stream>>>(src, dst, emask, cursor, sedge, E);

  // x -> bf16; weight prep
  k_tobf16<<<ceil_div(N * D, 1024), 256, 0, stream>>>(x, xb, N * D);
  k_prepw12<<<dim3(4, 4, 2 * L), 256, 0, stream>>>(w1, w2, w1t_hi, w2t_hi, L);
  k_prepw<<<dim3(F / 32, F / 32), 256, 0, stream>>>(l1w, l1t_hi, l1t_lo, F, F);

  const ushort* h_in = xb;
  for (int l = 0; l < L; ++l) {
    k_agg<<<ceil_div(N, 2), 128, 0, stream>>>(h_in, rowptr, sedge, eps, l, pooled, N);
    k_mlp<<<ceil_div(N, 64), 256, 0, stream>>>(
        pooled, w1t_hi + (size_t)l * D * H, b1 + (size_t)l * H,
        w2t_hi + (size_t)l * H * D, b2 + (size_t)l * D, hb[l], N);
    h_in = hb[l];
  }

  // all 6 graph-pools in one dispatch
  k_pool_all<<<dim3(G, L1), 128, 0, stream>>>(xb, hb[0], hb[1], hb[2], hb[3], hb[4],
                                              batch, pg, N, L1);

  // classifier: lin1 (relu, K=768, split W), lin2 + softmax
  k_mgemm<1, 0, 1><<<dim3(F / 64, ceil_div(G, 64)), 256, 0, stream>>>(
      pg, l1t_hi, l1t_lo, l1b, l1out, G, F, F);
  k_lin2_softmax<<<G, 64, 0, stream>>>(l1out, l2w, l2b, (float*)d_out, F, C);
}